// Round 2
// baseline (403.068 us; speedup 1.0000x reference)
//
#include <hip/hip_runtime.h>
#include <hip/hip_bf16.h>
#include <math.h>

// ---------------------------------------------------------------------------
// MultiModalEncoder collapses algebraically:
//   softmax of constant score matrices -> exactly 0.5 each
//   res_mv == res_pc == 0.5*(v_mv+v_pc) + max(v_mv,v_pc)          (q/k dead)
//   stage-2 attention of identical rows -> 2*v_c
//   h = r2 @ (Wv_c@Wp) + (2*bv_c@Wp + bp),  r2 = v_mv+v_pc+2*max(v_mv,v_pc)
// Then LayerNorm -> SELU -> L2 normalize per row.
//
// R2 structure: stage-1 computed TRANSPOSED (mfma(Wfrag, datafrag)) so the
// stage-1 output lands feature-major; stage-2 A-fragments are then gathered
// with in-wave shuffles (no LDS, no barrier). Split-precision bf16 (hi+lo,
// 3 MFMA products) keeps ~2^-16 relative error vs the f32 reference.
// ---------------------------------------------------------------------------

typedef float f32x4 __attribute__((ext_vector_type(4)));
typedef short s16x8 __attribute__((ext_vector_type(8)));   // 8 bf16 (4 VGPRs)

#define MFMA __builtin_amdgcn_mfma_f32_16x16x32_bf16

__device__ __forceinline__ unsigned short f2bf(float x) {
    __hip_bfloat16 h = __float2bfloat16(x);               // RNE, pairable cvt_pk
    return __builtin_bit_cast(unsigned short, h);
}
__device__ __forceinline__ float bf2f(unsigned short u) {
    return __builtin_bit_cast(float, ((unsigned)u) << 16);
}
__device__ __forceinline__ unsigned packsplit(float x) { // (lo<<16)|hi
    unsigned short h = f2bf(x);
    unsigned short l = f2bf(x - bf2f(h));
    return ((unsigned)l << 16) | (unsigned)h;
}

// ---------------- single prep kernel ---------------------------------------
// blocks 0..63   : pack Wv_mv fragments
// blocks 64..95  : pack Wv_pc fragments
// blocks 96..127 : pack W2 = Wv_c@Wp fragments (elements computed on the fly)
// block  128     : b2 = 2*(bv_c@Wp) + bp
// Fragment f = c*8 + t: lane l, elem i holds W[k=c*32+(l>>4)*8+i][t*16+(l&15)]
__global__ void prep_all(const float* __restrict__ Wv_mv, const float* __restrict__ Wv_pc,
                         const float* __restrict__ Wv_c,  const float* __restrict__ Wp,
                         const float* __restrict__ bv_c,  const float* __restrict__ bp,
                         unsigned short* __restrict__ Fmv, unsigned short* __restrict__ Fpc,
                         unsigned short* __restrict__ Fw2, float* __restrict__ b2) {
    int b = blockIdx.x;
    int l = threadIdx.x;                       // 0..63
    if (b < 128) {
        const float* W = nullptr;
        unsigned short* out = nullptr;
        int f;
        bool direct = true;
        if (b < 64)       { W = Wv_mv; out = Fmv; f = b; }
        else if (b < 96)  { W = Wv_pc; out = Fpc; f = b - 64; }
        else              { out = Fw2; f = b - 96; direct = false; }
        int c = f >> 3, t = f & 7;
        int col = t * 16 + (l & 15);
        int k0 = c * 32 + (l >> 4) * 8;
        unsigned short hi[8], lo[8];
        #pragma unroll
        for (int i = 0; i < 8; ++i) {
            float x;
            if (direct) {
                x = W[(size_t)(k0 + i) * 128 + col];
            } else {                            // W2[k0+i][col] = Wv_c row . Wp col
                float s = 0.f;
                for (int k = 0; k < 128; ++k)
                    s = fmaf(Wv_c[(size_t)(k0 + i) * 128 + k], Wp[(size_t)k * 128 + col], s);
                x = s;
            }
            unsigned short h = f2bf(x);
            hi[i] = h;
            lo[i] = f2bf(x - bf2f(h));
        }
        unsigned short* base = out + (size_t)f * 1024 + (size_t)l * 8;
        #pragma unroll
        for (int i = 0; i < 8; ++i) base[i] = hi[i];
        #pragma unroll
        for (int i = 0; i < 8; ++i) base[512 + i] = lo[i];
    } else {
        #pragma unroll
        for (int rep = 0; rep < 2; ++rep) {
            int j = l + rep * 64;
            float s = 0.f;
            for (int k = 0; k < 128; ++k) s = fmaf(bv_c[k], Wp[(size_t)k * 128 + j], s);
            b2[j] = 2.f * s + bp[j];
        }
    }
}

// ---------------- main fused kernel ----------------------------------------
// 256 threads = 4 independent waves; each wave owns 32 rows. No LDS.
// Stage-1 (transposed): acc[tf][ts] holds X^T[feat=tf*16+lg*4+j][row=ts*16+ll]
// Stage-2 (normal):     acch[ts][t] holds H[row=ts*16+lg*4+j][feat=t*16+ll]
__launch_bounds__(256, 3)
__global__ void fused_main(const float* __restrict__ mv, const float* __restrict__ pc,
                           const unsigned short* __restrict__ Fmv,
                           const unsigned short* __restrict__ Fpc,
                           const unsigned short* __restrict__ Fw2,
                           const float* __restrict__ b_mv, const float* __restrict__ b_pc,
                           const float* __restrict__ b2v,
                           const float* __restrict__ ln_g, const float* __restrict__ ln_b,
                           float* __restrict__ out) {
    const int tid = threadIdx.x;
    const int wv  = tid >> 6;
    const int l   = tid & 63;
    const int lg  = l >> 4;
    const int ll  = l & 15;
    const int rowbase = blockIdx.x * 128 + wv * 32;

    const f32x4 vz = {0.f, 0.f, 0.f, 0.f};

    // ---------------- stage 1a: X1^T = Wv_mv^T @ mv^T (K=256) --------------
    f32x4 acc1[8][2];
    #pragma unroll
    for (int tf = 0; tf < 8; ++tf) { acc1[tf][0] = vz; acc1[tf][1] = vz; }

    #pragma unroll 1
    for (int c = 0; c < 8; ++c) {
        s16x8 dh[2], dl[2];
        #pragma unroll
        for (int ts = 0; ts < 2; ++ts) {
            const float* ap = mv + (size_t)(rowbase + ts * 16 + ll) * 256 + c * 32 + lg * 8;
            f32x4 x0 = *(const f32x4*)ap;
            f32x4 x1 = *(const f32x4*)(ap + 4);
            #pragma unroll
            for (int i = 0; i < 4; ++i) {
                unsigned p0 = packsplit(x0[i]);
                dh[ts][i]     = (short)(p0 & 0xffffu);
                dl[ts][i]     = (short)(p0 >> 16);
                unsigned p1 = packsplit(x1[i]);
                dh[ts][4 + i] = (short)(p1 & 0xffffu);
                dl[ts][4 + i] = (short)(p1 >> 16);
            }
        }
        const unsigned short* fb = Fmv + (size_t)c * 8192 + (size_t)l * 8;
        #pragma unroll
        for (int tf = 0; tf < 8; ++tf) {
            s16x8 wh = *(const s16x8*)(fb + tf * 1024);
            s16x8 wl = *(const s16x8*)(fb + tf * 1024 + 512);
            #pragma unroll
            for (int ts = 0; ts < 2; ++ts) {
                acc1[tf][ts] = MFMA(wh, dh[ts], acc1[tf][ts], 0, 0, 0);
                acc1[tf][ts] = MFMA(wl, dh[ts], acc1[tf][ts], 0, 0, 0);
                acc1[tf][ts] = MFMA(wh, dl[ts], acc1[tf][ts], 0, 0, 0);
            }
        }
    }

    // ---------------- stage 1b: X2^T = Wv_pc^T @ pc^T (K=128) --------------
    f32x4 acc2[8][2];
    #pragma unroll
    for (int tf = 0; tf < 8; ++tf) { acc2[tf][0] = vz; acc2[tf][1] = vz; }

    #pragma unroll 1
    for (int c = 0; c < 4; ++c) {
        s16x8 dh[2], dl[2];
        #pragma unroll
        for (int ts = 0; ts < 2; ++ts) {
            const float* ap = pc + (size_t)(rowbase + ts * 16 + ll) * 128 + c * 32 + lg * 8;
            f32x4 x0 = *(const f32x4*)ap;
            f32x4 x1 = *(const f32x4*)(ap + 4);
            #pragma unroll
            for (int i = 0; i < 4; ++i) {
                unsigned p0 = packsplit(x0[i]);
                dh[ts][i]     = (short)(p0 & 0xffffu);
                dl[ts][i]     = (short)(p0 >> 16);
                unsigned p1 = packsplit(x1[i]);
                dh[ts][4 + i] = (short)(p1 & 0xffffu);
                dl[ts][4 + i] = (short)(p1 >> 16);
            }
        }
        const unsigned short* fb = Fpc + (size_t)c * 8192 + (size_t)l * 8;
        #pragma unroll
        for (int tf = 0; tf < 8; ++tf) {
            s16x8 wh = *(const s16x8*)(fb + tf * 1024);
            s16x8 wl = *(const s16x8*)(fb + tf * 1024 + 512);
            #pragma unroll
            for (int ts = 0; ts < 2; ++ts) {
                acc2[tf][ts] = MFMA(wh, dh[ts], acc2[tf][ts], 0, 0, 0);
                acc2[tf][ts] = MFMA(wl, dh[ts], acc2[tf][ts], 0, 0, 0);
                acc2[tf][ts] = MFMA(wh, dl[ts], acc2[tf][ts], 0, 0, 0);
            }
        }
    }

    // ---------- combine: r2 = x1 + x2 + 2*max(x1,x2), packed hi/lo ---------
    // lane holds r2[feat = tf*16 + lg*4 + j][row = ts*16 + ll]
    unsigned r2p[8][2][4];
    #pragma unroll
    for (int tf = 0; tf < 8; ++tf) {
        #pragma unroll
        for (int j = 0; j < 4; ++j) {
            float bm = b_mv[tf * 16 + lg * 4 + j];
            float bq = b_pc[tf * 16 + lg * 4 + j];
            #pragma unroll
            for (int ts = 0; ts < 2; ++ts) {
                float x1 = acc1[tf][ts][j] + bm;
                float x2 = acc2[tf][ts][j] + bq;
                float r2 = (x1 + x2) + 2.f * fmaxf(x1, x2);
                r2p[tf][ts][j] = packsplit(r2);
            }
        }
    }

    // ---------------- stage 2: H = r2 @ W2 (K=128), shuffle-gathered A -----
    // A-frag elem i: feat = c*32 + lg*8 + i, row = ts*16 + ll.
    // Holder lane: ((2*lg + (i>>2))&3)*16 + ll, reg r2p[2c + (lg>>1)][ts][i&3].
    f32x4 acch[2][8];
    #pragma unroll
    for (int ts = 0; ts < 2; ++ts)
        #pragma unroll
        for (int t = 0; t < 8; ++t) acch[ts][t] = vz;

    const int g0 = (((lg * 2)     ) & 3) * 16 + ll;
    const int g1 = (((lg * 2) + 1 ) & 3) * 16 + ll;
    const bool uhi = (lg & 2) != 0;

    #pragma unroll
    for (int c = 0; c < 4; ++c) {
        s16x8 ah[2], al[2];
        #pragma unroll
        for (int ts = 0; ts < 2; ++ts) {
            #pragma unroll
            for (int q = 0; q < 2; ++q) {
                const int src = q ? g1 : g0;
                #pragma unroll
                for (int j = 0; j < 4; ++j) {
                    unsigned va = __shfl(r2p[2 * c][ts][j], src);
                    unsigned vb = __shfl(r2p[2 * c + 1][ts][j], src);
                    unsigned v  = uhi ? vb : va;
                    ah[ts][q * 4 + j] = (short)(v & 0xffffu);
                    al[ts][q * 4 + j] = (short)(v >> 16);
                }
            }
        }
        const unsigned short* fb = Fw2 + (size_t)c * 8192 + (size_t)l * 8;
        #pragma unroll
        for (int t = 0; t < 8; ++t) {
            s16x8 bh = *(const s16x8*)(fb + t * 1024);
            s16x8 bl = *(const s16x8*)(fb + t * 1024 + 512);
            #pragma unroll
            for (int ts = 0; ts < 2; ++ts) {
                acch[ts][t] = MFMA(ah[ts], bh, acch[ts][t], 0, 0, 0);
                acch[ts][t] = MFMA(al[ts], bh, acch[ts][t], 0, 0, 0);
                acch[ts][t] = MFMA(ah[ts], bl, acch[ts][t], 0, 0, 0);
            }
        }
    }

    // ---------------- epilogue: +b2, LayerNorm, SELU, L2-normalize ---------
    float b2c[8], bg[8], bb[8];
    #pragma unroll
    for (int t = 0; t < 8; ++t) {
        b2c[t] = b2v[t * 16 + ll];
        bg[t]  = ln_g[t * 16 + ll];
        bb[t]  = ln_b[t * 16 + ll];
    }
    #pragma unroll
    for (int ts = 0; ts < 2; ++ts) {
        #pragma unroll
        for (int j = 0; j < 4; ++j) {
            float v[8];
            float sum = 0.f, ssq = 0.f;
            #pragma unroll
            for (int t = 0; t < 8; ++t) {
                float h = acch[ts][t][j] + b2c[t];
                v[t] = h;
                sum += h;
                ssq = fmaf(h, h, ssq);
            }
            #pragma unroll
            for (int o = 1; o < 16; o <<= 1) {
                sum += __shfl_xor(sum, o);
                ssq += __shfl_xor(ssq, o);
            }
            float mu  = sum * 0.0078125f;                   // /128
            float var = ssq * 0.0078125f - mu * mu;
            float rs  = 1.f / sqrtf(var + 1e-5f);
            float s2  = 0.f;
            #pragma unroll
            for (int t = 0; t < 8; ++t) {
                float hn = (v[t] - mu) * rs * bg[t] + bb[t];
                float m  = hn > 0.f ? hn : 1.6732632423543772f * expm1f(hn);
                m = 1.0507009873554805f * m;                // selu scale
                v[t] = m;
                s2 = fmaf(m, m, s2);
            }
            #pragma unroll
            for (int o = 1; o < 16; o <<= 1) s2 += __shfl_xor(s2, o);
            float sc = 1.f / (sqrtf(s2) + 1e-9f);
            int row = rowbase + ts * 16 + lg * 4 + j;
            float* op = out + (size_t)row * 128 + ll;
            #pragma unroll
            for (int t = 0; t < 8; ++t) op[t * 16] = v[t] * sc;
        }
    }
}

// ---------------------------------------------------------------------------
extern "C" void kernel_launch(void* const* d_in, const int* in_sizes, int n_in,
                              void* d_out, int out_size, void* d_ws, size_t ws_size,
                              hipStream_t stream) {
    const float* mv    = (const float*)d_in[0];
    const float* pc    = (const float*)d_in[1];
    const float* Wv_mv = (const float*)d_in[6];
    const float* bv_mv = (const float*)d_in[7];
    const float* Wv_pc = (const float*)d_in[12];
    const float* bv_pc = (const float*)d_in[13];
    const float* Wv_c  = (const float*)d_in[18];
    const float* bv_c  = (const float*)d_in[19];
    const float* Wp    = (const float*)d_in[20];
    const float* bp    = (const float*)d_in[21];
    const float* ln_g  = (const float*)d_in[22];
    const float* ln_b  = (const float*)d_in[23];
    float* out = (float*)d_out;

    char* ws = (char*)d_ws;
    unsigned short* Fmv = (unsigned short*)ws;              // 64 frag-pairs = 128 KB
    unsigned short* Fpc = Fmv + 65536;                      // 32 frag-pairs = 64 KB
    unsigned short* Fw2 = Fpc + 32768;                      // 32 frag-pairs = 64 KB
    float* b2 = (float*)(ws + 262144);                      // 128 f32

    prep_all<<<129, 64, 0, stream>>>(Wv_mv, Wv_pc, Wv_c, Wp, bv_c, bp,
                                     Fmv, Fpc, Fw2, b2);
    fused_main<<<1024, 256, 0, stream>>>(mv, pc, Fmv, Fpc, Fw2,
                                         bv_mv, bv_pc, b2, ln_g, ln_b, out);
}

// Round 6
// 381.297 us; speedup vs baseline: 1.0571x; 1.0571x over previous
//
#include <hip/hip_runtime.h>
#include <hip/hip_bf16.h>
#include <math.h>

// ---------------------------------------------------------------------------
// MultiModalEncoder collapses algebraically:
//   softmax of constant score matrices -> exactly 0.5 each
//   res_mv == res_pc == 0.5*(v_mv+v_pc) + max(v_mv,v_pc)          (q/k dead)
//   stage-2 attention of identical rows -> 2*v_c
//   h = r2 @ (Wv_c@Wp) + (2*bv_c@Wp + bp),  r2 = v_mv+v_pc+2*max(v_mv,v_pc)
// Then LayerNorm -> SELU -> L2 normalize per row.
//
// R6 == R5 == R4 (GPU acquisition timeouts; resubmit unchanged for a clean
// A/B against R2's measured 183 us / R1's 140 us).
//
// Design: 16 rows per wave end-to-end (regs ~halved vs R1 -> target
// 4 waves/SIMD), 32 KB LDS/block (private per-wave slices), XOR-swizzled
// r2 tile (conflict-free b32 writes and b128 reads), one __syncthreads
// before stage-2 reads for guaranteed LDS visibility. Numerics:
// split-precision bf16 (hi+lo, 3 MFMA products), f32 accumulate.
// ---------------------------------------------------------------------------

typedef float f32x4 __attribute__((ext_vector_type(4)));
typedef unsigned u32x4 __attribute__((ext_vector_type(4)));
typedef short s16x8 __attribute__((ext_vector_type(8)));   // 8 bf16 (4 VGPRs)

#define MFMA __builtin_amdgcn_mfma_f32_16x16x32_bf16

__device__ __forceinline__ unsigned short f2bf(float x) {
    __hip_bfloat16 h = __float2bfloat16(x);               // RNE
    return __builtin_bit_cast(unsigned short, h);
}
__device__ __forceinline__ float bf2f(unsigned short u) {
    return __builtin_bit_cast(float, ((unsigned)u) << 16);
}
__device__ __forceinline__ unsigned packsplit(float x) { // (lo<<16)|hi
    unsigned short h = f2bf(x);
    unsigned short l = f2bf(x - bf2f(h));
    return ((unsigned)l << 16) | (unsigned)h;
}

// ---------------- single prep kernel ---------------------------------------
// blocks 0..63   : pack Wv_mv fragments
// blocks 64..95  : pack Wv_pc fragments
// blocks 96..127 : pack W2 = Wv_c@Wp fragments (elements computed on the fly)
// block  128     : b2 = 2*(bv_c@Wp) + bp
// Fragment f = c*8 + t: lane l, elem i holds W[k=c*32+(l>>4)*8+i][t*16+(l&15)]
__global__ void prep_all(const float* __restrict__ Wv_mv, const float* __restrict__ Wv_pc,
                         const float* __restrict__ Wv_c,  const float* __restrict__ Wp,
                         const float* __restrict__ bv_c,  const float* __restrict__ bp,
                         unsigned short* __restrict__ Fmv, unsigned short* __restrict__ Fpc,
                         unsigned short* __restrict__ Fw2, float* __restrict__ b2) {
    int b = blockIdx.x;
    int l = threadIdx.x;                       // 0..63
    if (b < 128) {
        const float* W = nullptr;
        unsigned short* out = nullptr;
        int f;
        bool direct = true;
        if (b < 64)       { W = Wv_mv; out = Fmv; f = b; }
        else if (b < 96)  { W = Wv_pc; out = Fpc; f = b - 64; }
        else              { out = Fw2; f = b - 96; direct = false; }
        int c = f >> 3, t = f & 7;
        int col = t * 16 + (l & 15);
        int k0 = c * 32 + (l >> 4) * 8;
        unsigned short hi[8], lo[8];
        #pragma unroll
        for (int i = 0; i < 8; ++i) {
            float x;
            if (direct) {
                x = W[(size_t)(k0 + i) * 128 + col];
            } else {                            // W2[k0+i][col] = Wv_c row . Wp col
                float s = 0.f;
                for (int k = 0; k < 128; ++k)
                    s = fmaf(Wv_c[(size_t)(k0 + i) * 128 + k], Wp[(size_t)k * 128 + col], s);
                x = s;
            }
            unsigned short h = f2bf(x);
            hi[i] = h;
            lo[i] = f2bf(x - bf2f(h));
        }
        unsigned short* base = out + (size_t)f * 1024 + (size_t)l * 8;
        #pragma unroll
        for (int i = 0; i < 8; ++i) base[i] = hi[i];
        #pragma unroll
        for (int i = 0; i < 8; ++i) base[512 + i] = lo[i];
    } else {
        #pragma unroll
        for (int rep = 0; rep < 2; ++rep) {
            int j = l + rep * 64;
            float s = 0.f;
            for (int k = 0; k < 128; ++k) s = fmaf(bv_c[k], Wp[(size_t)k * 128 + j], s);
            b2[j] = 2.f * s + bp[j];
        }
    }
}

// ---------------- main fused kernel ----------------------------------------
// 256 threads = 4 independent waves; each wave owns 16 rows end-to-end.
// Per-wave LDS slice (8 KB) holds the swizzled r2 tile.
// Grid = 131072/64 = 2048 blocks.
__launch_bounds__(256, 4)
__global__ void fused_main(const float* __restrict__ mv, const float* __restrict__ pc,
                           const unsigned short* __restrict__ Fmv,
                           const unsigned short* __restrict__ Fpc,
                           const unsigned short* __restrict__ Fw2,
                           const float* __restrict__ b_mv, const float* __restrict__ b_pc,
                           const float* __restrict__ b2v,
                           const float* __restrict__ ln_g, const float* __restrict__ ln_b,
                           float* __restrict__ out) {
    __shared__ unsigned r2lds[4][2048];        // 32 KB total, 8 KB per wave
    const int tid = threadIdx.x;
    const int wv  = tid >> 6;
    const int l   = tid & 63;
    const int lg  = l >> 4;
    const int ll  = l & 15;
    const int rowbase = blockIdx.x * 64 + wv * 16;

    const f32x4 vz = {0.f, 0.f, 0.f, 0.f};

    // ---------------- stage 1a: X1 = mv @ Wv_mv (K=256) --------------------
    // A-frag: lane holds mv[row=rowbase+ll][k=c*32+lg*8+i]
    f32x4 acc1[8];
    #pragma unroll
    for (int tf = 0; tf < 8; ++tf) acc1[tf] = vz;

    #pragma unroll 2
    for (int c = 0; c < 8; ++c) {
        const float* ap = mv + (size_t)(rowbase + ll) * 256 + c * 32 + lg * 8;
        f32x4 x0 = *(const f32x4*)ap;
        f32x4 x1 = *(const f32x4*)(ap + 4);
        s16x8 dh, dl;
        #pragma unroll
        for (int i = 0; i < 4; ++i) {
            unsigned p0 = packsplit(x0[i]);
            dh[i]     = (short)(p0 & 0xffffu);
            dl[i]     = (short)(p0 >> 16);
            unsigned p1 = packsplit(x1[i]);
            dh[4 + i] = (short)(p1 & 0xffffu);
            dl[4 + i] = (short)(p1 >> 16);
        }
        const unsigned short* fb = Fmv + (size_t)c * 8192 + (size_t)l * 8;
        #pragma unroll
        for (int tf = 0; tf < 8; ++tf) {
            s16x8 wh = *(const s16x8*)(fb + tf * 1024);
            s16x8 wl = *(const s16x8*)(fb + tf * 1024 + 512);
            acc1[tf] = MFMA(dh, wh, acc1[tf], 0, 0, 0);
            acc1[tf] = MFMA(dl, wh, acc1[tf], 0, 0, 0);
            acc1[tf] = MFMA(dh, wl, acc1[tf], 0, 0, 0);
        }
    }

    // ---------------- stage 1b: X2 = pc @ Wv_pc (K=128) --------------------
    f32x4 acc2[8];
    #pragma unroll
    for (int tf = 0; tf < 8; ++tf) acc2[tf] = vz;

    #pragma unroll 2
    for (int c = 0; c < 4; ++c) {
        const float* ap = pc + (size_t)(rowbase + ll) * 128 + c * 32 + lg * 8;
        f32x4 x0 = *(const f32x4*)ap;
        f32x4 x1 = *(const f32x4*)(ap + 4);
        s16x8 dh, dl;
        #pragma unroll
        for (int i = 0; i < 4; ++i) {
            unsigned p0 = packsplit(x0[i]);
            dh[i]     = (short)(p0 & 0xffffu);
            dl[i]     = (short)(p0 >> 16);
            unsigned p1 = packsplit(x1[i]);
            dh[4 + i] = (short)(p1 & 0xffffu);
            dl[4 + i] = (short)(p1 >> 16);
        }
        const unsigned short* fb = Fpc + (size_t)c * 8192 + (size_t)l * 8;
        #pragma unroll
        for (int tf = 0; tf < 8; ++tf) {
            s16x8 wh = *(const s16x8*)(fb + tf * 1024);
            s16x8 wl = *(const s16x8*)(fb + tf * 1024 + 512);
            acc2[tf] = MFMA(dh, wh, acc2[tf], 0, 0, 0);
            acc2[tf] = MFMA(dl, wh, acc2[tf], 0, 0, 0);
            acc2[tf] = MFMA(dh, wl, acc2[tf], 0, 0, 0);
        }
    }

    // ---------- combine: r2 = x1 + x2 + 2*max(x1,x2) -> swizzled LDS -------
    // C-frag: row = lg*4+j (0..15), feat = tf*16+ll. Swizzle dw ^= (row&7)<<2.
    unsigned* base = &r2lds[wv][0];
    #pragma unroll
    for (int tf = 0; tf < 8; ++tf) {
        float bm = b_mv[tf * 16 + ll];
        float bq = b_pc[tf * 16 + ll];
        #pragma unroll
        for (int j = 0; j < 4; ++j) {
            int row = lg * 4 + j;
            float x1 = acc1[tf][j] + bm;
            float x2 = acc2[tf][j] + bq;
            float r2 = (x1 + x2) + 2.f * fmaxf(x1, x2);
            int dw = row * 128 + tf * 16 + ll;
            base[dw ^ ((row & 7) << 2)] = packsplit(r2);
        }
    }
    __syncthreads();   // guarantee cross-lane LDS visibility (cheap: once/kernel)

    // ---------------- stage 2: H = r2 @ W2 (K=128) -------------------------
    // A-frag: row = ll, feats k = c*32 + lg*8 + i  (two swizzled b128 reads)
    f32x4 acch[8];
    #pragma unroll
    for (int t = 0; t < 8; ++t) acch[t] = vz;

    #pragma unroll
    for (int c = 0; c < 4; ++c) {
        s16x8 ah, al;
        #pragma unroll
        for (int q = 0; q < 2; ++q) {
            int dw = ll * 128 + c * 32 + lg * 8 + q * 4;
            u32x4 u = *(const u32x4*)&base[dw ^ ((ll & 7) << 2)];
            #pragma unroll
            for (int j = 0; j < 4; ++j) {
                ah[q * 4 + j] = (short)(u[j] & 0xffffu);
                al[q * 4 + j] = (short)(u[j] >> 16);
            }
        }
        const unsigned short* fb = Fw2 + (size_t)c * 8192 + (size_t)l * 8;
        #pragma unroll
        for (int t = 0; t < 8; ++t) {
            s16x8 wh = *(const s16x8*)(fb + t * 1024);
            s16x8 wl = *(const s16x8*)(fb + t * 1024 + 512);
            acch[t] = MFMA(ah, wh, acch[t], 0, 0, 0);
            acch[t] = MFMA(al, wh, acch[t], 0, 0, 0);
            acch[t] = MFMA(ah, wl, acch[t], 0, 0, 0);
        }
    }

    // ---------------- epilogue: +b2, LayerNorm, SELU, L2-normalize ---------
    float b2c[8], bg[8], bb[8];
    #pragma unroll
    for (int t = 0; t < 8; ++t) {
        b2c[t] = b2v[t * 16 + ll];
        bg[t]  = ln_g[t * 16 + ll];
        bb[t]  = ln_b[t * 16 + ll];
    }
    #pragma unroll
    for (int j = 0; j < 4; ++j) {
        float v[8];
        float sum = 0.f, ssq = 0.f;
        #pragma unroll
        for (int t = 0; t < 8; ++t) {
            float h = acch[t][j] + b2c[t];
            v[t] = h;
            sum += h;
            ssq = fmaf(h, h, ssq);
        }
        #pragma unroll
        for (int o = 1; o < 16; o <<= 1) {
            sum += __shfl_xor(sum, o);
            ssq += __shfl_xor(ssq, o);
        }
        float mu  = sum * 0.0078125f;                   // /128
        float var = ssq * 0.0078125f - mu * mu;
        float rs  = 1.f / sqrtf(var + 1e-5f);
        float s2  = 0.f;
        #pragma unroll
        for (int t = 0; t < 8; ++t) {
            float hn = (v[t] - mu) * rs * bg[t] + bb[t];
            float m  = hn > 0.f ? hn : 1.6732632423543772f * expm1f(hn);
            m = 1.0507009873554805f * m;                // selu scale
            v[t] = m;
            s2 = fmaf(m, m, s2);
        }
        #pragma unroll
        for (int o = 1; o < 16; o <<= 1) s2 += __shfl_xor(s2, o);
        float sc = 1.f / (sqrtf(s2) + 1e-9f);
        int row = rowbase + lg * 4 + j;
        float* op = out + (size_t)row * 128 + ll;
        #pragma unroll
        for (int t = 0; t < 8; ++t) op[t * 16] = v[t] * sc;
    }
}

// ---------------------------------------------------------------------------
extern "C" void kernel_launch(void* const* d_in, const int* in_sizes, int n_in,
                              void* d_out, int out_size, void* d_ws, size_t ws_size,
                              hipStream_t stream) {
    const float* mv    = (const float*)d_in[0];
    const float* pc    = (const float*)d_in[1];
    const float* Wv_mv = (const float*)d_in[6];
    const float* bv_mv = (const float*)d_in[7];
    const float* Wv_pc = (const float*)d_in[12];
    const float* bv_pc = (const float*)d_in[13];
    const float* Wv_c  = (const float*)d_in[18];
    const float* bv_c  = (const float*)d_in[19];
    const float* Wp    = (const float*)d_in[20];
    const float* bp    = (const float*)d_in[21];
    const float* ln_g  = (const float*)d_in[22];
    const float* ln_b  = (const float*)d_in[23];
    float* out = (float*)d_out;

    char* ws = (char*)d_ws;
    unsigned short* Fmv = (unsigned short*)ws;              // 64 frag-pairs = 128 KB
    unsigned short* Fpc = Fmv + 65536;                      // 32 frag-pairs = 64 KB
    unsigned short* Fw2 = Fpc + 32768;                      // 32 frag-pairs = 64 KB
    float* b2 = (float*)(ws + 262144);                      // 128 f32

    prep_all<<<129, 64, 0, stream>>>(Wv_mv, Wv_pc, Wv_c, Wp, bv_c, bp,
                                     Fmv, Fpc, Fw2, b2);
    fused_main<<<2048, 256, 0, stream>>>(mv, pc, Fmv, Fpc, Fw2,
                                         bv_mv, bv_pc, b2, ln_g, ln_b, out);
}